// Round 3
// baseline (648.475 us; speedup 1.0000x reference)
//
#include <hip/hip_runtime.h>
#include <hip/hip_bf16.h>

#define DD 256
#define NGN 80000
#define NMN 20000
#define NEE 160000

typedef unsigned short u16;
typedef __attribute__((ext_vector_type(8))) short s16x8;
typedef __attribute__((ext_vector_type(4))) short s16x4;
typedef __attribute__((ext_vector_type(4))) float f32x4;

__device__ __forceinline__ u16 f2bf(float f) {
  union { float f; unsigned u; } v; v.f = f;
  unsigned r = (v.u + 0x7FFFu + ((v.u >> 16) & 1u)) >> 16;
  return (u16)r;
}
__device__ __forceinline__ float bf2f(u16 x) {
  union { unsigned u; float f; } v; v.u = ((unsigned)x) << 16;
  return v.f;
}

// Pack fp32 weight [K][256] -> bf16 fragment-linear layout [kt][nt][lane][8]
// slot->k bijection: k = kt*32 + 4*(lane>>4) + (i<4 ? i : 12+i); n = nt*16 + (lane&15)
__global__ void pack_weights(const float* __restrict__ W, u16* __restrict__ dst, int K) {
  int idx = blockIdx.x * 256 + threadIdx.x;
  if (idx >= K * 256) return;
  int i = idx & 7;
  int lane = (idx >> 3) & 63;
  int nt = (idx >> 9) & 15;
  int kt = idx >> 13;
  int k = kt * 32 + 4 * (lane >> 4) + (i < 4 ? i : 12 + i);
  int n = nt * 16 + (lane & 15);
  dst[idx] = f2bf(W[(size_t)k * 256 + n]);
}

// ---------------- CSR build ----------------
__global__ void csr_hist(const int* __restrict__ didx, int* __restrict__ cnt) {
  int i = blockIdx.x * 256 + threadIdx.x;
  if (i < NEE) atomicAdd(cnt + didx[i], 1);
}
__global__ void csr_scan(const int* __restrict__ cnt, int* __restrict__ cursor) {
  __shared__ int psum[256];
  const int CH = (NMN + 255) / 256;  // 79
  int t = threadIdx.x;
  int base = t * CH, s = 0;
  for (int k = 0; k < CH; ++k) { int i = base + k; if (i < NMN) s += cnt[i]; }
  psum[t] = s;
  __syncthreads();
  for (int off = 1; off < 256; off <<= 1) {
    int v = (t >= off) ? psum[t - off] : 0;
    __syncthreads();
    psum[t] += v;
    __syncthreads();
  }
  int run = psum[t] - s;  // exclusive prefix
  for (int k = 0; k < CH; ++k) {
    int i = base + k;
    if (i < NMN) { cursor[i] = run; run += cnt[i]; }
  }
}
__global__ void csr_fill(const int* __restrict__ didx, int* __restrict__ cursor,
                         int* __restrict__ eids) {
  int e = blockIdx.x * 256 + threadIdx.x;
  if (e < NEE) { int p = atomicAdd(cursor + didx[e], 1); eids[p] = e; }
}

// A-fragment from swizzled LDS tile (rows 64 x 256 bf16, row pitch 512B)
__device__ __forceinline__ s16x8 ldsA(const u16* uni, int rowL, int cL) {
  int swz = (rowL & 7) << 4;
  s16x4 lo = *(const s16x4*)((const char*)uni + rowL * 512 + ((cL * 2) ^ swz));
  s16x4 hi = *(const s16x4*)((const char*)uni + rowL * 512 + (((cL + 16) * 2) ^ swz));
  s16x8 a;
#pragma unroll
  for (int j = 0; j < 4; ++j) { a[j] = lo[j]; a[4 + j] = hi[j]; }
  return a;
}

// Dense GEMM: Y(bf16)[n][256] = X(fp32)[n][256] @ Wp (packed); B read direct from global
__global__ __launch_bounds__(256, 4) void gemm_ns(
    const float* __restrict__ X, const u16* __restrict__ Wp,
    u16* __restrict__ Y, int n) {
  __shared__ u16 uni[16384];
  const int tid = threadIdx.x;
  const int lane = tid & 63;
  const int wave = tid >> 6;
  const int mr = wave >> 1, nc = wave & 1;
  const int g = lane >> 4, lr = lane & 15;
  const int row0 = blockIdx.x * 64;

  // stage X tile -> uni (bf16 swizzled), coalesced 32B/lane
#pragma unroll
  for (int j = 0; j < 8; ++j) {
    int e = wave * 16 + j * 2 + (lane >> 5);
    int r = min(row0 + e, n - 1);
    const float* src = X + (size_t)r * DD + (lane & 31) * 8;
    f32x4 f0 = *(const f32x4*)src;
    f32x4 f1 = *(const f32x4*)(src + 4);
    s16x8 o;
#pragma unroll
    for (int k = 0; k < 4; ++k) { o[k] = (short)f2bf(f0[k]); o[4 + k] = (short)f2bf(f1[k]); }
    int co = (lane & 31) * 8;
    *(s16x8*)((char*)uni + e * 512 + ((co * 2) ^ ((e & 7) << 4))) = o;
  }
  __syncthreads();

  const f32x4 fz = {0.f, 0.f, 0.f, 0.f};
  f32x4 acc[2][8];
#pragma unroll
  for (int mt = 0; mt < 2; ++mt)
#pragma unroll
    for (int nt = 0; nt < 8; ++nt) acc[mt][nt] = fz;

  for (int kl = 0; kl < 8; ++kl) {
    s16x8 afr[2];
#pragma unroll
    for (int mt = 0; mt < 2; ++mt) afr[mt] = ldsA(uni, mr * 32 + mt * 16 + lr, kl * 32 + 4 * g);
#pragma unroll
    for (int h = 0; h < 2; ++h) {
      s16x8 bfr[4];
#pragma unroll
      for (int q = 0; q < 4; ++q)
        bfr[q] = *(const s16x8*)(Wp + (size_t)kl * 8192 + ((nc * 8 + h * 4 + q) * 64 + lane) * 8);
#pragma unroll
      for (int q = 0; q < 4; ++q) {
        acc[0][h * 4 + q] = __builtin_amdgcn_mfma_f32_16x16x32_bf16(afr[0], bfr[q], acc[0][h * 4 + q], 0, 0, 0);
        acc[1][h * 4 + q] = __builtin_amdgcn_mfma_f32_16x16x32_bf16(afr[1], bfr[q], acc[1][h * 4 + q], 0, 0, 0);
      }
    }
  }
  __syncthreads();
  // bounce through uni for coalesced store
#pragma unroll
  for (int mt = 0; mt < 2; ++mt)
#pragma unroll
    for (int nt = 0; nt < 8; ++nt)
#pragma unroll
      for (int i = 0; i < 4; ++i) {
        int rowL = mr * 32 + mt * 16 + 4 * g + i;
        int col = nc * 128 + nt * 16 + lr;
        *(u16*)((char*)uni + rowL * 512 + ((col * 2) ^ ((rowL & 7) << 4))) = f2bf(acc[mt][nt][i]);
      }
  __syncthreads();
#pragma unroll
  for (int rr = 0; rr < 16; ++rr) {
    int rowL = wave * 16 + rr;
    int rg = row0 + rowL;
    if (rg < n) {
      s16x4 v = *(const s16x4*)((char*)uni + rowL * 512 + ((lane * 8) ^ ((rowL & 7) << 4)));
      *(s16x4*)(Y + (size_t)rg * DD + lane * 4) = v;
    }
  }
}

// Edge kernel over CSR-ordered edges; run-reduced scatter (1 atomic per block-node-col)
__global__ __launch_bounds__(256, 4) void edge_fused(
    const float* __restrict__ efeat,
    const u16* __restrict__ GSp, const u16* __restrict__ GMp,
    const int* __restrict__ sidx, const int* __restrict__ eids,
    const u16* __restrict__ W1p, const float* __restrict__ b1,
    const u16* __restrict__ W2p, const float* __restrict__ b2,
    const float* __restrict__ gam, const float* __restrict__ bet,
    const int* __restrict__ didx, float* __restrict__ agg) {
  __shared__ u16 uni[16384];        // 32 KB: gsm -> efeat tile -> h -> LN rows
  __shared__ float2 pstats[64][2];  // 1 KB
  __shared__ int eidL[64];
  __shared__ int srcL[64];
  __shared__ int dstL[64];

  const int tid = threadIdx.x;
  const int lane = tid & 63;
  const int wave = tid >> 6;
  const int mr = wave >> 1, nc = wave & 1;
  const int g = lane >> 4, lr = lane & 15;
  const int row0 = blockIdx.x * 64;

  // Phase 0: edge ids + endpoints for this block
  if (tid < 64) {
    int e = eids[row0 + tid];
    eidL[tid] = e;
    srcL[tid] = sidx[e];
    dstL[tid] = didx[e];
  }
  __syncthreads();

  // Phase 1: gather GS[src]+GM[dst] -> uni (bf16 swizzled)
#pragma unroll
  for (int j = 0; j < 8; ++j) {
    int e = wave * 16 + j * 2 + (lane >> 5);
    int co = (lane & 31) * 8;
    s16x8 a = *(const s16x8*)(GSp + (size_t)srcL[e] * DD + co);
    s16x8 b = *(const s16x8*)(GMp + (size_t)dstL[e] * DD + co);
    s16x8 o;
#pragma unroll
    for (int k = 0; k < 8; ++k) o[k] = (short)f2bf(bf2f((u16)a[k]) + bf2f((u16)b[k]));
    *(s16x8*)((char*)uni + e * 512 + ((co * 2) ^ ((e & 7) << 4))) = o;
  }
  __syncthreads();

  // Phase 2: C-init accumulators from uni
  f32x4 acc[2][8];
#pragma unroll
  for (int mt = 0; mt < 2; ++mt)
#pragma unroll
    for (int nt = 0; nt < 8; ++nt)
#pragma unroll
      for (int i = 0; i < 4; ++i) {
        int rowL = mr * 32 + mt * 16 + 4 * g + i;
        int col = nc * 128 + nt * 16 + lr;
        acc[mt][nt][i] = bf2f(*(const u16*)((char*)uni + rowL * 512 + ((col * 2) ^ ((rowL & 7) << 4))));
      }
  __syncthreads();

  // Phase 3: gather efeat rows -> uni (bf16 swizzled), coalesced 32B/lane
#pragma unroll
  for (int j = 0; j < 8; ++j) {
    int e = wave * 16 + j * 2 + (lane >> 5);
    const float* src = efeat + (size_t)eidL[e] * DD + (lane & 31) * 8;
    f32x4 f0 = *(const f32x4*)src;
    f32x4 f1 = *(const f32x4*)(src + 4);
    s16x8 o;
#pragma unroll
    for (int k = 0; k < 4; ++k) { o[k] = (short)f2bf(f0[k]); o[4 + k] = (short)f2bf(f1[k]); }
    int co = (lane & 31) * 8;
    *(s16x8*)((char*)uni + e * 512 + ((co * 2) ^ ((e & 7) << 4))) = o;
  }
  __syncthreads();

  // Phase 4: GEMM1 (K=256, efeat part), B direct from global
  for (int kl = 0; kl < 8; ++kl) {
    s16x8 afr[2];
#pragma unroll
    for (int mt = 0; mt < 2; ++mt) afr[mt] = ldsA(uni, mr * 32 + mt * 16 + lr, kl * 32 + 4 * g);
#pragma unroll
    for (int h = 0; h < 2; ++h) {
      s16x8 bfr[4];
#pragma unroll
      for (int q = 0; q < 4; ++q)
        bfr[q] = *(const s16x8*)(W1p + (size_t)kl * 8192 + ((nc * 8 + h * 4 + q) * 64 + lane) * 8);
#pragma unroll
      for (int q = 0; q < 4; ++q) {
        acc[0][h * 4 + q] = __builtin_amdgcn_mfma_f32_16x16x32_bf16(afr[0], bfr[q], acc[0][h * 4 + q], 0, 0, 0);
        acc[1][h * 4 + q] = __builtin_amdgcn_mfma_f32_16x16x32_bf16(afr[1], bfr[q], acc[1][h * 4 + q], 0, 0, 0);
      }
    }
  }
  __syncthreads();

  // Phase 5: bias1 + SiLU -> uni
  {
    float b1v[8];
#pragma unroll
    for (int nt = 0; nt < 8; ++nt) b1v[nt] = b1[nc * 128 + nt * 16 + lr];
#pragma unroll
    for (int mt = 0; mt < 2; ++mt)
#pragma unroll
      for (int nt = 0; nt < 8; ++nt)
#pragma unroll
        for (int i = 0; i < 4; ++i) {
          float x = acc[mt][nt][i] + b1v[nt];
          float h = x / (1.f + __expf(-x));
          int rowL = mr * 32 + mt * 16 + 4 * g + i;
          int col = nc * 128 + nt * 16 + lr;
          *(u16*)((char*)uni + rowL * 512 + ((col * 2) ^ ((rowL & 7) << 4))) = f2bf(h);
        }
  }
  __syncthreads();

  // Phase 6: GEMM2
  f32x4 acc2[2][8];
  const f32x4 fz = {0.f, 0.f, 0.f, 0.f};
#pragma unroll
  for (int mt = 0; mt < 2; ++mt)
#pragma unroll
    for (int nt = 0; nt < 8; ++nt) acc2[mt][nt] = fz;
  for (int kl = 0; kl < 8; ++kl) {
    s16x8 afr[2];
#pragma unroll
    for (int mt = 0; mt < 2; ++mt) afr[mt] = ldsA(uni, mr * 32 + mt * 16 + lr, kl * 32 + 4 * g);
#pragma unroll
    for (int h = 0; h < 2; ++h) {
      s16x8 bfr[4];
#pragma unroll
      for (int q = 0; q < 4; ++q)
        bfr[q] = *(const s16x8*)(W2p + (size_t)kl * 8192 + ((nc * 8 + h * 4 + q) * 64 + lane) * 8);
#pragma unroll
      for (int q = 0; q < 4; ++q) {
        acc2[0][h * 4 + q] = __builtin_amdgcn_mfma_f32_16x16x32_bf16(afr[0], bfr[q], acc2[0][h * 4 + q], 0, 0, 0);
        acc2[1][h * 4 + q] = __builtin_amdgcn_mfma_f32_16x16x32_bf16(afr[1], bfr[q], acc2[1][h * 4 + q], 0, 0, 0);
      }
    }
  }

  // Phase 7: bias2 + LN stats
  float b2v[8], gv[8], bv[8];
#pragma unroll
  for (int nt = 0; nt < 8; ++nt) {
    int col = nc * 128 + nt * 16 + lr;
    b2v[nt] = b2[col];
    gv[nt] = gam[col];
    bv[nt] = bet[col];
  }
#pragma unroll
  for (int mt = 0; mt < 2; ++mt)
#pragma unroll
    for (int i = 0; i < 4; ++i) {
      float s = 0.f, s2 = 0.f;
#pragma unroll
      for (int nt = 0; nt < 8; ++nt) {
        float y = acc2[mt][nt][i] + b2v[nt];
        s += y;
        s2 += y * y;
      }
#pragma unroll
      for (int m = 1; m < 16; m <<= 1) {
        s += __shfl_xor(s, m);
        s2 += __shfl_xor(s2, m);
      }
      if (lr == 0) pstats[mr * 32 + mt * 16 + 4 * g + i][nc] = make_float2(s, s2);
    }
  __syncthreads();  // also: all GEMM2 LDS reads done

  // Phase 8: LN rows -> uni (bf16 swizzled)
#pragma unroll
  for (int mt = 0; mt < 2; ++mt)
#pragma unroll
    for (int i = 0; i < 4; ++i) {
      int rowL = mr * 32 + mt * 16 + 4 * g + i;
      float2 pa = pstats[rowL][0], pb = pstats[rowL][1];
      float sum = pa.x + pb.x, sq = pa.y + pb.y;
      float mu = sum * (1.f / 256.f);
      float var = fmaxf(sq * (1.f / 256.f) - mu * mu, 0.f);
      float rs = rsqrtf(var + 1e-5f);
#pragma unroll
      for (int nt = 0; nt < 8; ++nt) {
        int col = nc * 128 + nt * 16 + lr;
        float y = acc2[mt][nt][i] + b2v[nt];
        float val = (y - mu) * rs * gv[nt] + bv[nt];
        *(u16*)((char*)uni + rowL * 512 + ((col * 2) ^ ((rowL & 7) << 4))) = f2bf(val);
      }
    }
  __syncthreads();

  // Phase 9: per-column run reduction over CSR-sorted rows -> 1 atomic per run
  {
    int c = tid;  // 0..255
    float sum = 0.f;
    int prev = dstL[0];
#pragma unroll 8
    for (int r = 0; r < 64; ++r) {
      int d = dstL[r];
      if (d != prev) {
        atomicAdd(agg + (size_t)prev * DD + c, sum);
        sum = 0.f;
        prev = d;
      }
      sum += bf2f(*(const u16*)((char*)uni + r * 512 + ((c * 2) ^ ((r & 7) << 4))));
    }
    atomicAdd(agg + (size_t)prev * DD + c, sum);
  }
}

// MODE 1: src/grid MLP (K1=256) -> residual write
// MODE 2: dst/mesh MLP (concat[agg|mesh], K1=512) -> residual write
template <int MODE, int K1>
__global__ __launch_bounds__(256, 4) void mlp_fused(
    const float* __restrict__ xa, const float* __restrict__ xb,
    const u16* __restrict__ W1p, const float* __restrict__ b1,
    const u16* __restrict__ W2p, const float* __restrict__ b2,
    const float* __restrict__ gam, const float* __restrict__ bet,
    const float* __restrict__ resid, float* __restrict__ out, int nrows) {
  __shared__ u16 uni[16384];
  __shared__ float2 pstats[64][2];

  const int tid = threadIdx.x;
  const int lane = tid & 63;
  const int wave = tid >> 6;
  const int mr = wave >> 1, nc = wave & 1;
  const int g = lane >> 4, lr = lane & 15;
  const int row0 = blockIdx.x * 64;

  const f32x4 fz = {0.f, 0.f, 0.f, 0.f};
  f32x4 acc[2][8];
#pragma unroll
  for (int mt = 0; mt < 2; ++mt)
#pragma unroll
    for (int nt = 0; nt < 8; ++nt) acc[mt][nt] = fz;

#pragma unroll
  for (int region = 0; region < K1 / 256; ++region) {
    __syncthreads();  // previous-region LDS reads complete
    const float* Xr = (region == 0) ? xa : xb;
#pragma unroll
    for (int j = 0; j < 8; ++j) {
      int e = wave * 16 + j * 2 + (lane >> 5);
      int r = min(row0 + e, nrows - 1);
      const float* src = Xr + (size_t)r * DD + (lane & 31) * 8;
      f32x4 f0 = *(const f32x4*)src;
      f32x4 f1 = *(const f32x4*)(src + 4);
      s16x8 o;
#pragma unroll
      for (int k = 0; k < 4; ++k) { o[k] = (short)f2bf(f0[k]); o[4 + k] = (short)f2bf(f1[k]); }
      int co = (lane & 31) * 8;
      *(s16x8*)((char*)uni + e * 512 + ((co * 2) ^ ((e & 7) << 4))) = o;
    }
    __syncthreads();
    for (int kl = 0; kl < 8; ++kl) {
      const int kt = region * 8 + kl;
      s16x8 afr[2];
#pragma unroll
      for (int mt = 0; mt < 2; ++mt) afr[mt] = ldsA(uni, mr * 32 + mt * 16 + lr, kl * 32 + 4 * g);
#pragma unroll
      for (int h = 0; h < 2; ++h) {
        s16x8 bfr[4];
#pragma unroll
        for (int q = 0; q < 4; ++q)
          bfr[q] = *(const s16x8*)(W1p + (size_t)kt * 8192 + ((nc * 8 + h * 4 + q) * 64 + lane) * 8);
#pragma unroll
        for (int q = 0; q < 4; ++q) {
          acc[0][h * 4 + q] = __builtin_amdgcn_mfma_f32_16x16x32_bf16(afr[0], bfr[q], acc[0][h * 4 + q], 0, 0, 0);
          acc[1][h * 4 + q] = __builtin_amdgcn_mfma_f32_16x16x32_bf16(afr[1], bfr[q], acc[1][h * 4 + q], 0, 0, 0);
        }
      }
    }
  }
  __syncthreads();

  // bias1 + SiLU -> uni
  {
    float b1v[8];
#pragma unroll
    for (int nt = 0; nt < 8; ++nt) b1v[nt] = b1[nc * 128 + nt * 16 + lr];
#pragma unroll
    for (int mt = 0; mt < 2; ++mt)
#pragma unroll
      for (int nt = 0; nt < 8; ++nt)
#pragma unroll
        for (int i = 0; i < 4; ++i) {
          float x = acc[mt][nt][i] + b1v[nt];
          float h = x / (1.f + __expf(-x));
          int rowL = mr * 32 + mt * 16 + 4 * g + i;
          int col = nc * 128 + nt * 16 + lr;
          *(u16*)((char*)uni + rowL * 512 + ((col * 2) ^ ((rowL & 7) << 4))) = f2bf(h);
        }
  }
  __syncthreads();

  f32x4 acc2[2][8];
#pragma unroll
  for (int mt = 0; mt < 2; ++mt)
#pragma unroll
    for (int nt = 0; nt < 8; ++nt) acc2[mt][nt] = fz;
  for (int kl = 0; kl < 8; ++kl) {
    s16x8 afr[2];
#pragma unroll
    for (int mt = 0; mt < 2; ++mt) afr[mt] = ldsA(uni, mr * 32 + mt * 16 + lr, kl * 32 + 4 * g);
#pragma unroll
    for (int h = 0; h < 2; ++h) {
      s16x8 bfr[4];
#pragma unroll
      for (int q = 0; q < 4; ++q)
        bfr[q] = *(const s16x8*)(W2p + (size_t)kl * 8192 + ((nc * 8 + h * 4 + q) * 64 + lane) * 8);
#pragma unroll
      for (int q = 0; q < 4; ++q) {
        acc2[0][h * 4 + q] = __builtin_amdgcn_mfma_f32_16x16x32_bf16(afr[0], bfr[q], acc2[0][h * 4 + q], 0, 0, 0);
        acc2[1][h * 4 + q] = __builtin_amdgcn_mfma_f32_16x16x32_bf16(afr[1], bfr[q], acc2[1][h * 4 + q], 0, 0, 0);
      }
    }
  }

  float b2v[8], gv[8], bv[8];
#pragma unroll
  for (int nt = 0; nt < 8; ++nt) {
    int col = nc * 128 + nt * 16 + lr;
    b2v[nt] = b2[col];
    gv[nt] = gam[col];
    bv[nt] = bet[col];
  }
#pragma unroll
  for (int mt = 0; mt < 2; ++mt)
#pragma unroll
    for (int i = 0; i < 4; ++i) {
      float s = 0.f, s2 = 0.f;
#pragma unroll
      for (int nt = 0; nt < 8; ++nt) {
        float y = acc2[mt][nt][i] + b2v[nt];
        s += y;
        s2 += y * y;
      }
#pragma unroll
      for (int m = 1; m < 16; m <<= 1) {
        s += __shfl_xor(s, m);
        s2 += __shfl_xor(s2, m);
      }
      if (lr == 0) pstats[mr * 32 + mt * 16 + 4 * g + i][nc] = make_float2(s, s2);
    }
  __syncthreads();
#pragma unroll
  for (int mt = 0; mt < 2; ++mt)
#pragma unroll
    for (int i = 0; i < 4; ++i) {
      int rowL = mr * 32 + mt * 16 + 4 * g + i;
      float2 pa = pstats[rowL][0], pb = pstats[rowL][1];
      float sum = pa.x + pb.x, sq = pa.y + pb.y;
      float mu = sum * (1.f / 256.f);
      float var = fmaxf(sq * (1.f / 256.f) - mu * mu, 0.f);
      float rs = rsqrtf(var + 1e-5f);
      int rg = row0 + rowL;
      if (MODE == 2 && rg >= nrows) continue;
#pragma unroll
      for (int nt = 0; nt < 8; ++nt) {
        int col = nc * 128 + nt * 16 + lr;
        float y = acc2[mt][nt][i] + b2v[nt];
        float val = (y - mu) * rs * gv[nt] + bv[nt];
        out[(size_t)rg * DD + col] = resid[(size_t)rg * DD + col] + val;
      }
    }
}

extern "C" void kernel_launch(void* const* d_in, const int* in_sizes, int n_in,
                              void* d_out, int out_size, void* d_ws, size_t ws_size,
                              hipStream_t stream) {
  const float* g2m  = (const float*)d_in[0];
  const float* grid = (const float*)d_in[1];
  const float* mesh = (const float*)d_in[2];
  const int* sidx = (const int*)d_in[3];
  const int* didx = (const int*)d_in[4];
  const float* eW1 = (const float*)d_in[5];
  const float* eb1 = (const float*)d_in[6];
  const float* eW2 = (const float*)d_in[7];
  const float* eb2 = (const float*)d_in[8];
  const float* eg  = (const float*)d_in[9];
  const float* ebt = (const float*)d_in[10];
  const float* sW1 = (const float*)d_in[11];
  const float* sb1 = (const float*)d_in[12];
  const float* sW2 = (const float*)d_in[13];
  const float* sb2 = (const float*)d_in[14];
  const float* sg  = (const float*)d_in[15];
  const float* sbt = (const float*)d_in[16];
  const float* dW1 = (const float*)d_in[17];
  const float* db1 = (const float*)d_in[18];
  const float* dW2 = (const float*)d_in[19];
  const float* db2 = (const float*)d_in[20];
  const float* dg  = (const float*)d_in[21];
  const float* dbt = (const float*)d_in[22];

  // workspace layout
  char* w = (char*)d_ws;
  float* agg = (float*)w;                                   // 20,480,000 B
  u16* wp = (u16*)(w + 20480000);                           // 1,179,648 B
  int* cnt = (int*)(w + 20480000 + 1179648);                // 81,920 B
  int* cursor = cnt + 20480;                                // 81,920 B
  int* eids = cursor + 20480;                               // 640,000 B

  u16* eW1p = wp;                 // 24 slabs: 0-7 efeat, 8-15 src, 16-23 dst
  u16* eW2p = eW1p + 768 * 256;
  u16* sW1p = eW2p + 256 * 256;
  u16* sW2p = sW1p + 256 * 256;
  u16* dW1p = sW2p + 256 * 256;
  u16* dW2p = dW1p + 512 * 256;

  float* gout = (float*)d_out;
  float* mout = gout + (size_t)NGN * DD;
  // GS/GM scratch in grid-output half of d_out (clobbered; MODE1 rewrites it last)
  u16* GSp = (u16*)d_out;                // 40.96 MB
  u16* GMp = GSp + (size_t)NGN * DD;     // 10.24 MB

  (void)hipMemsetAsync(agg, 0, 20480000, stream);
  (void)hipMemsetAsync(cnt, 0, 81920, stream);

  pack_weights<<<768, 256, 0, stream>>>(eW1, eW1p, 768);
  pack_weights<<<256, 256, 0, stream>>>(eW2, eW2p, 256);
  pack_weights<<<256, 256, 0, stream>>>(sW1, sW1p, 256);
  pack_weights<<<256, 256, 0, stream>>>(sW2, sW2p, 256);
  pack_weights<<<512, 256, 0, stream>>>(dW1, dW1p, 512);
  pack_weights<<<256, 256, 0, stream>>>(dW2, dW2p, 256);

  csr_hist<<<(NEE + 255) / 256, 256, 0, stream>>>(didx, cnt);
  csr_scan<<<1, 256, 0, stream>>>(cnt, cursor);
  csr_fill<<<(NEE + 255) / 256, 256, 0, stream>>>(didx, cursor, eids);

  gemm_ns<<<NGN / 64, 256, 0, stream>>>(grid, eW1p + 8 * 8192, GSp, NGN);
  gemm_ns<<<(NMN + 63) / 64, 256, 0, stream>>>(mesh, eW1p + 16 * 8192, GMp, NMN);

  edge_fused<<<NEE / 64, 256, 0, stream>>>(
      g2m, GSp, GMp, sidx, eids, eW1p, eb1, eW2p, eb2, eg, ebt, didx, agg);

  mlp_fused<2, 512><<<(NMN + 63) / 64, 256, 0, stream>>>(
      agg, mesh, dW1p, db1, dW2p, db2, dg, dbt, mesh, mout, NMN);
  mlp_fused<1, 256><<<NGN / 64, 256, 0, stream>>>(
      grid, nullptr, sW1p, sb1, sW2p, sb2, sg, sbt, grid, gout, NGN);
}

// Round 4
// 426.012 us; speedup vs baseline: 1.5222x; 1.5222x over previous
//
#include <hip/hip_runtime.h>
#include <hip/hip_bf16.h>

#define DD 256
#define NGN 80000
#define NMN 20000
#define NEE 160000

typedef unsigned short u16;
typedef __attribute__((ext_vector_type(8))) short s16x8;
typedef __attribute__((ext_vector_type(4))) short s16x4;
typedef __attribute__((ext_vector_type(4))) float f32x4;

__device__ __forceinline__ u16 f2bf(float f) {
  union { float f; unsigned u; } v; v.f = f;
  unsigned r = (v.u + 0x7FFFu + ((v.u >> 16) & 1u)) >> 16;
  return (u16)r;
}
__device__ __forceinline__ float bf2f(u16 x) {
  union { unsigned u; float f; } v; v.u = ((unsigned)x) << 16;
  return v.f;
}

// Pack fp32 weight [K][256] -> bf16 fragment-linear layout [kt][nt][lane][8]
// slot->k bijection: k = kt*32 + 4*(lane>>4) + (i<4 ? i : 12+i); n = nt*16 + (lane&15)
__global__ void pack_weights(const float* __restrict__ W, u16* __restrict__ dst, int K) {
  int idx = blockIdx.x * 256 + threadIdx.x;
  if (idx >= K * 256) return;
  int i = idx & 7;
  int lane = (idx >> 3) & 63;
  int nt = (idx >> 9) & 15;
  int kt = idx >> 13;
  int k = kt * 32 + 4 * (lane >> 4) + (i < 4 ? i : 12 + i);
  int n = nt * 16 + (lane & 15);
  dst[idx] = f2bf(W[(size_t)k * 256 + n]);
}

// ---------------- CSR build ----------------
__global__ void csr_hist(const int* __restrict__ didx, int* __restrict__ cnt) {
  int i = blockIdx.x * 256 + threadIdx.x;
  if (i < NEE) atomicAdd(cnt + didx[i], 1);
}
__global__ void csr_scan(const int* __restrict__ cnt, int* __restrict__ cursor) {
  __shared__ int psum[256];
  const int CH = (NMN + 255) / 256;  // 79
  int t = threadIdx.x;
  int base = t * CH, s = 0;
  for (int k = 0; k < CH; ++k) { int i = base + k; if (i < NMN) s += cnt[i]; }
  psum[t] = s;
  __syncthreads();
  for (int off = 1; off < 256; off <<= 1) {
    int v = (t >= off) ? psum[t - off] : 0;
    __syncthreads();
    psum[t] += v;
    __syncthreads();
  }
  int run = psum[t] - s;  // exclusive prefix
  for (int k = 0; k < CH; ++k) {
    int i = base + k;
    if (i < NMN) { cursor[i] = run; run += cnt[i]; }
  }
}
__global__ void csr_fill(const int* __restrict__ didx, int* __restrict__ cursor,
                         int* __restrict__ eids) {
  int e = blockIdx.x * 256 + threadIdx.x;
  if (e < NEE) { int p = atomicAdd(cursor + didx[e], 1); eids[p] = e; }
}

// A-fragment from swizzled LDS tile (rows 64 x 256 bf16, row pitch 512B)
__device__ __forceinline__ s16x8 ldsA(const u16* uni, int rowL, int cL) {
  int swz = (rowL & 7) << 4;
  s16x4 lo = *(const s16x4*)((const char*)uni + rowL * 512 + ((cL * 2) ^ swz));
  s16x4 hi = *(const s16x4*)((const char*)uni + rowL * 512 + (((cL + 16) * 2) ^ swz));
  s16x8 a;
#pragma unroll
  for (int j = 0; j < 4; ++j) { a[j] = lo[j]; a[4 + j] = hi[j]; }
  return a;
}

// Dense GEMM: Y(bf16)[n][256] = X(fp32)[n][256] @ Wp (packed); B read direct from global
__global__ __launch_bounds__(256, 2) void gemm_ns(
    const float* __restrict__ X, const u16* __restrict__ Wp,
    u16* __restrict__ Y, int n) {
  __shared__ u16 uni[16384];
  const int tid = threadIdx.x;
  const int lane = tid & 63;
  const int wave = tid >> 6;
  const int mr = wave >> 1, nc = wave & 1;
  const int g = lane >> 4, lr = lane & 15;
  const int row0 = blockIdx.x * 64;

  // stage X tile -> uni (bf16 swizzled), coalesced 32B/lane
#pragma unroll
  for (int j = 0; j < 8; ++j) {
    int e = wave * 16 + j * 2 + (lane >> 5);
    int r = min(row0 + e, n - 1);
    const float* src = X + (size_t)r * DD + (lane & 31) * 8;
    f32x4 f0 = *(const f32x4*)src;
    f32x4 f1 = *(const f32x4*)(src + 4);
    s16x8 o;
#pragma unroll
    for (int k = 0; k < 4; ++k) { o[k] = (short)f2bf(f0[k]); o[4 + k] = (short)f2bf(f1[k]); }
    int co = (lane & 31) * 8;
    *(s16x8*)((char*)uni + e * 512 + ((co * 2) ^ ((e & 7) << 4))) = o;
  }
  __syncthreads();

  const f32x4 fz = {0.f, 0.f, 0.f, 0.f};
  f32x4 acc[2][8];
#pragma unroll
  for (int mt = 0; mt < 2; ++mt)
#pragma unroll
    for (int nt = 0; nt < 8; ++nt) acc[mt][nt] = fz;

  for (int kl = 0; kl < 8; ++kl) {
    s16x8 afr[2];
#pragma unroll
    for (int mt = 0; mt < 2; ++mt) afr[mt] = ldsA(uni, mr * 32 + mt * 16 + lr, kl * 32 + 4 * g);
#pragma unroll
    for (int h = 0; h < 2; ++h) {
      s16x8 bfr[4];
#pragma unroll
      for (int q = 0; q < 4; ++q)
        bfr[q] = *(const s16x8*)(Wp + (size_t)kl * 8192 + ((nc * 8 + h * 4 + q) * 64 + lane) * 8);
#pragma unroll
      for (int q = 0; q < 4; ++q) {
        acc[0][h * 4 + q] = __builtin_amdgcn_mfma_f32_16x16x32_bf16(afr[0], bfr[q], acc[0][h * 4 + q], 0, 0, 0);
        acc[1][h * 4 + q] = __builtin_amdgcn_mfma_f32_16x16x32_bf16(afr[1], bfr[q], acc[1][h * 4 + q], 0, 0, 0);
      }
    }
  }
  __syncthreads();
  // bounce through uni for coalesced store
#pragma unroll
  for (int mt = 0; mt < 2; ++mt)
#pragma unroll
    for (int nt = 0; nt < 8; ++nt)
#pragma unroll
      for (int i = 0; i < 4; ++i) {
        int rowL = mr * 32 + mt * 16 + 4 * g + i;
        int col = nc * 128 + nt * 16 + lr;
        *(u16*)((char*)uni + rowL * 512 + ((col * 2) ^ ((rowL & 7) << 4))) = f2bf(acc[mt][nt][i]);
      }
  __syncthreads();
#pragma unroll
  for (int rr = 0; rr < 16; ++rr) {
    int rowL = wave * 16 + rr;
    int rg = row0 + rowL;
    if (rg < n) {
      s16x4 v = *(const s16x4*)((char*)uni + rowL * 512 + ((lane * 8) ^ ((rowL & 7) << 4)));
      *(s16x4*)(Y + (size_t)rg * DD + lane * 4) = v;
    }
  }
}

// Edge kernel over CSR-ordered edges; run-reduced scatter (1 atomic per block-node-col)
__global__ __launch_bounds__(256, 2) void edge_fused(
    const float* __restrict__ efeat,
    const u16* __restrict__ GSp, const u16* __restrict__ GMp,
    const int* __restrict__ sidx, const int* __restrict__ eids,
    const u16* __restrict__ W1p, const float* __restrict__ b1,
    const u16* __restrict__ W2p, const float* __restrict__ b2,
    const float* __restrict__ gam, const float* __restrict__ bet,
    const int* __restrict__ didx, float* __restrict__ agg) {
  __shared__ u16 uni[16384];        // 32 KB: gsm -> efeat tile -> h -> LN rows
  __shared__ float2 pstats[64][2];  // 1 KB
  __shared__ int eidL[64];
  __shared__ int srcL[64];
  __shared__ int dstL[64];

  const int tid = threadIdx.x;
  const int lane = tid & 63;
  const int wave = tid >> 6;
  const int mr = wave >> 1, nc = wave & 1;
  const int g = lane >> 4, lr = lane & 15;
  const int row0 = blockIdx.x * 64;

  // Phase 0: edge ids + endpoints for this block
  if (tid < 64) {
    int e = eids[row0 + tid];
    eidL[tid] = e;
    srcL[tid] = sidx[e];
    dstL[tid] = didx[e];
  }
  __syncthreads();

  // Phase 1: gather GS[src]+GM[dst] -> uni (bf16 swizzled)
#pragma unroll
  for (int j = 0; j < 8; ++j) {
    int e = wave * 16 + j * 2 + (lane >> 5);
    int co = (lane & 31) * 8;
    s16x8 a = *(const s16x8*)(GSp + (size_t)srcL[e] * DD + co);
    s16x8 b = *(const s16x8*)(GMp + (size_t)dstL[e] * DD + co);
    s16x8 o;
#pragma unroll
    for (int k = 0; k < 8; ++k) o[k] = (short)f2bf(bf2f((u16)a[k]) + bf2f((u16)b[k]));
    *(s16x8*)((char*)uni + e * 512 + ((co * 2) ^ ((e & 7) << 4))) = o;
  }
  __syncthreads();

  // Phase 2: C-init accumulators from uni
  f32x4 acc[2][8];
#pragma unroll
  for (int mt = 0; mt < 2; ++mt)
#pragma unroll
    for (int nt = 0; nt < 8; ++nt)
#pragma unroll
      for (int i = 0; i < 4; ++i) {
        int rowL = mr * 32 + mt * 16 + 4 * g + i;
        int col = nc * 128 + nt * 16 + lr;
        acc[mt][nt][i] = bf2f(*(const u16*)((char*)uni + rowL * 512 + ((col * 2) ^ ((rowL & 7) << 4))));
      }
  __syncthreads();

  // Phase 3: gather efeat rows -> uni (bf16 swizzled), coalesced 32B/lane
#pragma unroll
  for (int j = 0; j < 8; ++j) {
    int e = wave * 16 + j * 2 + (lane >> 5);
    const float* src = efeat + (size_t)eidL[e] * DD + (lane & 31) * 8;
    f32x4 f0 = *(const f32x4*)src;
    f32x4 f1 = *(const f32x4*)(src + 4);
    s16x8 o;
#pragma unroll
    for (int k = 0; k < 4; ++k) { o[k] = (short)f2bf(f0[k]); o[4 + k] = (short)f2bf(f1[k]); }
    int co = (lane & 31) * 8;
    *(s16x8*)((char*)uni + e * 512 + ((co * 2) ^ ((e & 7) << 4))) = o;
  }
  __syncthreads();

  // Phase 4: GEMM1 (K=256, efeat part), B direct from global
  for (int kl = 0; kl < 8; ++kl) {
    s16x8 afr[2];
#pragma unroll
    for (int mt = 0; mt < 2; ++mt) afr[mt] = ldsA(uni, mr * 32 + mt * 16 + lr, kl * 32 + 4 * g);
#pragma unroll
    for (int h = 0; h < 2; ++h) {
      s16x8 bfr[4];
#pragma unroll
      for (int q = 0; q < 4; ++q)
        bfr[q] = *(const s16x8*)(W1p + (size_t)kl * 8192 + ((nc * 8 + h * 4 + q) * 64 + lane) * 8);
#pragma unroll
      for (int q = 0; q < 4; ++q) {
        acc[0][h * 4 + q] = __builtin_amdgcn_mfma_f32_16x16x32_bf16(afr[0], bfr[q], acc[0][h * 4 + q], 0, 0, 0);
        acc[1][h * 4 + q] = __builtin_amdgcn_mfma_f32_16x16x32_bf16(afr[1], bfr[q], acc[1][h * 4 + q], 0, 0, 0);
      }
    }
  }
  __syncthreads();

  // Phase 5: bias1 + SiLU -> uni
  {
    float b1v[8];
#pragma unroll
    for (int nt = 0; nt < 8; ++nt) b1v[nt] = b1[nc * 128 + nt * 16 + lr];
#pragma unroll
    for (int mt = 0; mt < 2; ++mt)
#pragma unroll
      for (int nt = 0; nt < 8; ++nt)
#pragma unroll
        for (int i = 0; i < 4; ++i) {
          float x = acc[mt][nt][i] + b1v[nt];
          float h = x / (1.f + __expf(-x));
          int rowL = mr * 32 + mt * 16 + 4 * g + i;
          int col = nc * 128 + nt * 16 + lr;
          *(u16*)((char*)uni + rowL * 512 + ((col * 2) ^ ((rowL & 7) << 4))) = f2bf(h);
        }
  }
  __syncthreads();

  // Phase 6: GEMM2
  f32x4 acc2[2][8];
  const f32x4 fz = {0.f, 0.f, 0.f, 0.f};
#pragma unroll
  for (int mt = 0; mt < 2; ++mt)
#pragma unroll
    for (int nt = 0; nt < 8; ++nt) acc2[mt][nt] = fz;
  for (int kl = 0; kl < 8; ++kl) {
    s16x8 afr[2];
#pragma unroll
    for (int mt = 0; mt < 2; ++mt) afr[mt] = ldsA(uni, mr * 32 + mt * 16 + lr, kl * 32 + 4 * g);
#pragma unroll
    for (int h = 0; h < 2; ++h) {
      s16x8 bfr[4];
#pragma unroll
      for (int q = 0; q < 4; ++q)
        bfr[q] = *(const s16x8*)(W2p + (size_t)kl * 8192 + ((nc * 8 + h * 4 + q) * 64 + lane) * 8);
#pragma unroll
      for (int q = 0; q < 4; ++q) {
        acc2[0][h * 4 + q] = __builtin_amdgcn_mfma_f32_16x16x32_bf16(afr[0], bfr[q], acc2[0][h * 4 + q], 0, 0, 0);
        acc2[1][h * 4 + q] = __builtin_amdgcn_mfma_f32_16x16x32_bf16(afr[1], bfr[q], acc2[1][h * 4 + q], 0, 0, 0);
      }
    }
  }

  // Phase 7: bias2 + LN stats
  float b2v[8], gv[8], bv[8];
#pragma unroll
  for (int nt = 0; nt < 8; ++nt) {
    int col = nc * 128 + nt * 16 + lr;
    b2v[nt] = b2[col];
    gv[nt] = gam[col];
    bv[nt] = bet[col];
  }
#pragma unroll
  for (int mt = 0; mt < 2; ++mt)
#pragma unroll
    for (int i = 0; i < 4; ++i) {
      float s = 0.f, s2 = 0.f;
#pragma unroll
      for (int nt = 0; nt < 8; ++nt) {
        float y = acc2[mt][nt][i] + b2v[nt];
        s += y;
        s2 += y * y;
      }
#pragma unroll
      for (int m = 1; m < 16; m <<= 1) {
        s += __shfl_xor(s, m);
        s2 += __shfl_xor(s2, m);
      }
      if (lr == 0) pstats[mr * 32 + mt * 16 + 4 * g + i][nc] = make_float2(s, s2);
    }
  __syncthreads();  // also: all GEMM2 LDS reads done

  // Phase 8: LN rows -> uni (bf16 swizzled)
#pragma unroll
  for (int mt = 0; mt < 2; ++mt)
#pragma unroll
    for (int i = 0; i < 4; ++i) {
      int rowL = mr * 32 + mt * 16 + 4 * g + i;
      float2 pa = pstats[rowL][0], pb = pstats[rowL][1];
      float sum = pa.x + pb.x, sq = pa.y + pb.y;
      float mu = sum * (1.f / 256.f);
      float var = fmaxf(sq * (1.f / 256.f) - mu * mu, 0.f);
      float rs = rsqrtf(var + 1e-5f);
#pragma unroll
      for (int nt = 0; nt < 8; ++nt) {
        int col = nc * 128 + nt * 16 + lr;
        float y = acc2[mt][nt][i] + b2v[nt];
        float val = (y - mu) * rs * gv[nt] + bv[nt];
        *(u16*)((char*)uni + rowL * 512 + ((col * 2) ^ ((rowL & 7) << 4))) = f2bf(val);
      }
    }
  __syncthreads();

  // Phase 9: per-column run reduction over CSR-sorted rows -> 1 atomic per run
  {
    int c = tid;  // 0..255
    float sum = 0.f;
    int prev = dstL[0];
#pragma unroll 8
    for (int r = 0; r < 64; ++r) {
      int d = dstL[r];
      if (d != prev) {
        atomicAdd(agg + (size_t)prev * DD + c, sum);
        sum = 0.f;
        prev = d;
      }
      sum += bf2f(*(const u16*)((char*)uni + r * 512 + ((c * 2) ^ ((r & 7) << 4))));
    }
    atomicAdd(agg + (size_t)prev * DD + c, sum);
  }
}

// MODE 1: src/grid MLP (K1=256) -> residual write
// MODE 2: dst/mesh MLP (concat[agg|mesh], K1=512) -> residual write
template <int MODE, int K1>
__global__ __launch_bounds__(256, 2) void mlp_fused(
    const float* __restrict__ xa, const float* __restrict__ xb,
    const u16* __restrict__ W1p, const float* __restrict__ b1,
    const u16* __restrict__ W2p, const float* __restrict__ b2,
    const float* __restrict__ gam, const float* __restrict__ bet,
    const float* __restrict__ resid, float* __restrict__ out, int nrows) {
  __shared__ u16 uni[16384];
  __shared__ float2 pstats[64][2];

  const int tid = threadIdx.x;
  const int lane = tid & 63;
  const int wave = tid >> 6;
  const int mr = wave >> 1, nc = wave & 1;
  const int g = lane >> 4, lr = lane & 15;
  const int row0 = blockIdx.x * 64;

  const f32x4 fz = {0.f, 0.f, 0.f, 0.f};
  f32x4 acc[2][8];
#pragma unroll
  for (int mt = 0; mt < 2; ++mt)
#pragma unroll
    for (int nt = 0; nt < 8; ++nt) acc[mt][nt] = fz;

#pragma unroll
  for (int region = 0; region < K1 / 256; ++region) {
    __syncthreads();  // previous-region LDS reads complete
    const float* Xr = (region == 0) ? xa : xb;
#pragma unroll
    for (int j = 0; j < 8; ++j) {
      int e = wave * 16 + j * 2 + (lane >> 5);
      int r = min(row0 + e, nrows - 1);
      const float* src = Xr + (size_t)r * DD + (lane & 31) * 8;
      f32x4 f0 = *(const f32x4*)src;
      f32x4 f1 = *(const f32x4*)(src + 4);
      s16x8 o;
#pragma unroll
      for (int k = 0; k < 4; ++k) { o[k] = (short)f2bf(f0[k]); o[4 + k] = (short)f2bf(f1[k]); }
      int co = (lane & 31) * 8;
      *(s16x8*)((char*)uni + e * 512 + ((co * 2) ^ ((e & 7) << 4))) = o;
    }
    __syncthreads();
    for (int kl = 0; kl < 8; ++kl) {
      const int kt = region * 8 + kl;
      s16x8 afr[2];
#pragma unroll
      for (int mt = 0; mt < 2; ++mt) afr[mt] = ldsA(uni, mr * 32 + mt * 16 + lr, kl * 32 + 4 * g);
#pragma unroll
      for (int h = 0; h < 2; ++h) {
        s16x8 bfr[4];
#pragma unroll
        for (int q = 0; q < 4; ++q)
          bfr[q] = *(const s16x8*)(W1p + (size_t)kt * 8192 + ((nc * 8 + h * 4 + q) * 64 + lane) * 8);
#pragma unroll
        for (int q = 0; q < 4; ++q) {
          acc[0][h * 4 + q] = __builtin_amdgcn_mfma_f32_16x16x32_bf16(afr[0], bfr[q], acc[0][h * 4 + q], 0, 0, 0);
          acc[1][h * 4 + q] = __builtin_amdgcn_mfma_f32_16x16x32_bf16(afr[1], bfr[q], acc[1][h * 4 + q], 0, 0, 0);
        }
      }
    }
  }
  __syncthreads();

  // bias1 + SiLU -> uni
  {
    float b1v[8];
#pragma unroll
    for (int nt = 0; nt < 8; ++nt) b1v[nt] = b1[nc * 128 + nt * 16 + lr];
#pragma unroll
    for (int mt = 0; mt < 2; ++mt)
#pragma unroll
      for (int nt = 0; nt < 8; ++nt)
#pragma unroll
        for (int i = 0; i < 4; ++i) {
          float x = acc[mt][nt][i] + b1v[nt];
          float h = x / (1.f + __expf(-x));
          int rowL = mr * 32 + mt * 16 + 4 * g + i;
          int col = nc * 128 + nt * 16 + lr;
          *(u16*)((char*)uni + rowL * 512 + ((col * 2) ^ ((rowL & 7) << 4))) = f2bf(h);
        }
  }
  __syncthreads();

  f32x4 acc2[2][8];
#pragma unroll
  for (int mt = 0; mt < 2; ++mt)
#pragma unroll
    for (int nt = 0; nt < 8; ++nt) acc2[mt][nt] = fz;
  for (int kl = 0; kl < 8; ++kl) {
    s16x8 afr[2];
#pragma unroll
    for (int mt = 0; mt < 2; ++mt) afr[mt] = ldsA(uni, mr * 32 + mt * 16 + lr, kl * 32 + 4 * g);
#pragma unroll
    for (int h = 0; h < 2; ++h) {
      s16x8 bfr[4];
#pragma unroll
      for (int q = 0; q < 4; ++q)
        bfr[q] = *(const s16x8*)(W2p + (size_t)kl * 8192 + ((nc * 8 + h * 4 + q) * 64 + lane) * 8);
#pragma unroll
      for (int q = 0; q < 4; ++q) {
        acc2[0][h * 4 + q] = __builtin_amdgcn_mfma_f32_16x16x32_bf16(afr[0], bfr[q], acc2[0][h * 4 + q], 0, 0, 0);
        acc2[1][h * 4 + q] = __builtin_amdgcn_mfma_f32_16x16x32_bf16(afr[1], bfr[q], acc2[1][h * 4 + q], 0, 0, 0);
      }
    }
  }

  float b2v[8], gv[8], bv[8];
#pragma unroll
  for (int nt = 0; nt < 8; ++nt) {
    int col = nc * 128 + nt * 16 + lr;
    b2v[nt] = b2[col];
    gv[nt] = gam[col];
    bv[nt] = bet[col];
  }
#pragma unroll
  for (int mt = 0; mt < 2; ++mt)
#pragma unroll
    for (int i = 0; i < 4; ++i) {
      float s = 0.f, s2 = 0.f;
#pragma unroll
      for (int nt = 0; nt < 8; ++nt) {
        float y = acc2[mt][nt][i] + b2v[nt];
        s += y;
        s2 += y * y;
      }
#pragma unroll
      for (int m = 1; m < 16; m <<= 1) {
        s += __shfl_xor(s, m);
        s2 += __shfl_xor(s2, m);
      }
      if (lr == 0) pstats[mr * 32 + mt * 16 + 4 * g + i][nc] = make_float2(s, s2);
    }
  __syncthreads();
#pragma unroll
  for (int mt = 0; mt < 2; ++mt)
#pragma unroll
    for (int i = 0; i < 4; ++i) {
      int rowL = mr * 32 + mt * 16 + 4 * g + i;
      float2 pa = pstats[rowL][0], pb = pstats[rowL][1];
      float sum = pa.x + pb.x, sq = pa.y + pb.y;
      float mu = sum * (1.f / 256.f);
      float var = fmaxf(sq * (1.f / 256.f) - mu * mu, 0.f);
      float rs = rsqrtf(var + 1e-5f);
      int rg = row0 + rowL;
      if (MODE == 2 && rg >= nrows) continue;
#pragma unroll
      for (int nt = 0; nt < 8; ++nt) {
        int col = nc * 128 + nt * 16 + lr;
        float y = acc2[mt][nt][i] + b2v[nt];
        float val = (y - mu) * rs * gv[nt] + bv[nt];
        out[(size_t)rg * DD + col] = resid[(size_t)rg * DD + col] + val;
      }
    }
}

extern "C" void kernel_launch(void* const* d_in, const int* in_sizes, int n_in,
                              void* d_out, int out_size, void* d_ws, size_t ws_size,
                              hipStream_t stream) {
  const float* g2m  = (const float*)d_in[0];
  const float* grid = (const float*)d_in[1];
  const float* mesh = (const float*)d_in[2];
  const int* sidx = (const int*)d_in[3];
  const int* didx = (const int*)d_in[4];
  const float* eW1 = (const float*)d_in[5];
  const float* eb1 = (const float*)d_in[6];
  const float* eW2 = (const float*)d_in[7];
  const float* eb2 = (const float*)d_in[8];
  const float* eg  = (const float*)d_in[9];
  const float* ebt = (const float*)d_in[10];
  const float* sW1 = (const float*)d_in[11];
  const float* sb1 = (const float*)d_in[12];
  const float* sW2 = (const float*)d_in[13];
  const float* sb2 = (const float*)d_in[14];
  const float* sg  = (const float*)d_in[15];
  const float* sbt = (const float*)d_in[16];
  const float* dW1 = (const float*)d_in[17];
  const float* db1 = (const float*)d_in[18];
  const float* dW2 = (const float*)d_in[19];
  const float* db2 = (const float*)d_in[20];
  const float* dg  = (const float*)d_in[21];
  const float* dbt = (const float*)d_in[22];

  // workspace layout
  char* w = (char*)d_ws;
  float* agg = (float*)w;                                   // 20,480,000 B
  u16* wp = (u16*)(w + 20480000);                           // 1,179,648 B
  int* cnt = (int*)(w + 20480000 + 1179648);                // 81,920 B
  int* cursor = cnt + 20480;                                // 81,920 B
  int* eids = cursor + 20480;                               // 640,000 B

  u16* eW1p = wp;                 // 24 slabs: 0-7 efeat, 8-15 src, 16-23 dst
  u16* eW2p = eW1p + 768 * 256;
  u16* sW1p = eW2p + 256 * 256;
  u16* sW2p = sW1p + 256 * 256;
  u16* dW1p = sW2p + 256 * 256;
  u16* dW2p = dW1p + 512 * 256;

  float* gout = (float*)d_out;
  float* mout = gout + (size_t)NGN * DD;
  // GS/GM scratch in grid-output half of d_out (clobbered; MODE1 rewrites it last)
  u16* GSp = (u16*)d_out;                // 40.96 MB
  u16* GMp = GSp + (size_t)NGN * DD;     // 10.24 MB

  (void)hipMemsetAsync(agg, 0, 20480000, stream);
  (void)hipMemsetAsync(cnt, 0, 81920, stream);

  pack_weights<<<768, 256, 0, stream>>>(eW1, eW1p, 768);
  pack_weights<<<256, 256, 0, stream>>>(eW2, eW2p, 256);
  pack_weights<<<256, 256, 0, stream>>>(sW1, sW1p, 256);
  pack_weights<<<256, 256, 0, stream>>>(sW2, sW2p, 256);
  pack_weights<<<512, 256, 0, stream>>>(dW1, dW1p, 512);
  pack_weights<<<256, 256, 0, stream>>>(dW2, dW2p, 256);

  csr_hist<<<(NEE + 255) / 256, 256, 0, stream>>>(didx, cnt);
  csr_scan<<<1, 256, 0, stream>>>(cnt, cursor);
  csr_fill<<<(NEE + 255) / 256, 256, 0, stream>>>(didx, cursor, eids);

  gemm_ns<<<NGN / 64, 256, 0, stream>>>(grid, eW1p + 8 * 8192, GSp, NGN);
  gemm_ns<<<(NMN + 63) / 64, 256, 0, stream>>>(mesh, eW1p + 16 * 8192, GMp, NMN);

  edge_fused<<<NEE / 64, 256, 0, stream>>>(
      g2m, GSp, GMp, sidx, eids, eW1p, eb1, eW2p, eb2, eg, ebt, didx, agg);

  mlp_fused<2, 512><<<(NMN + 63) / 64, 256, 0, stream>>>(
      agg, mesh, dW1p, db1, dW2p, db2, dg, dbt, mesh, mout, NMN);
  mlp_fused<1, 256><<<NGN / 64, 256, 0, stream>>>(
      grid, nullptr, sW1p, sb1, sW2p, sb2, sg, sbt, grid, gout, NGN);
}

// Round 5
// 360.594 us; speedup vs baseline: 1.7983x; 1.1814x over previous
//
#include <hip/hip_runtime.h>
#include <hip/hip_bf16.h>

#define DD 256
#define NGN 80000
#define NMN 20000
#define NEE 160000

typedef unsigned short u16;
typedef __attribute__((ext_vector_type(8))) short s16x8;
typedef __attribute__((ext_vector_type(4))) short s16x4;
typedef __attribute__((ext_vector_type(4))) float f32x4;

__device__ __forceinline__ u16 f2bf(float f) {
  __hip_bfloat16 h = __float2bfloat16(f);  // HW cvt (packs to v_cvt_pk_bf16_f32)
  union { __hip_bfloat16 h; u16 u; } v; v.h = h;
  return v.u;
}
__device__ __forceinline__ float bf2f(u16 x) {
  union { unsigned u; float f; } v; v.u = ((unsigned)x) << 16;
  return v.f;
}

// A-fragment from swizzled LDS tile (rows 64 x 256 bf16, row pitch 512B)
__device__ __forceinline__ s16x8 ldsA(const u16* uni, int rowL, int cL) {
  int swz = (rowL & 7) << 4;
  s16x4 lo = *(const s16x4*)((const char*)uni + rowL * 512 + ((cL * 2) ^ swz));
  s16x4 hi = *(const s16x4*)((const char*)uni + rowL * 512 + (((cL + 16) * 2) ^ swz));
  s16x8 a;
#pragma unroll
  for (int j = 0; j < 4; ++j) { a[j] = lo[j]; a[4 + j] = hi[j]; }
  return a;
}

// ---------------- fused pack(6 weights) + csr histogram ----------------
__global__ void pack_hist(const float* __restrict__ eW1, const float* __restrict__ eW2,
                          const float* __restrict__ sW1, const float* __restrict__ sW2,
                          const float* __restrict__ dW1, const float* __restrict__ dW2,
                          u16* __restrict__ wp, const int* __restrict__ didx,
                          int* __restrict__ cnt) {
  int bid = blockIdx.x;
  if (bid < 2304) {
    const float* W; u16* dst; int lb;
    if (bid < 768)       { W = eW1; dst = wp;              lb = bid; }
    else if (bid < 1024) { W = eW2; dst = wp + 768 * 256;  lb = bid - 768; }
    else if (bid < 1280) { W = sW1; dst = wp + 1024 * 256; lb = bid - 1024; }
    else if (bid < 1536) { W = sW2; dst = wp + 1280 * 256; lb = bid - 1280; }
    else if (bid < 2048) { W = dW1; dst = wp + 1536 * 256; lb = bid - 1536; }
    else                 { W = dW2; dst = wp + 2048 * 256; lb = bid - 2048; }
    int idx = lb * 256 + threadIdx.x;
    int i = idx & 7, lane = (idx >> 3) & 63, nt = (idx >> 9) & 15, kt = idx >> 13;
    int k = kt * 32 + 4 * (lane >> 4) + (i < 4 ? i : 12 + i);
    int n = nt * 16 + (lane & 15);
    dst[idx] = f2bf(W[(size_t)k * 256 + n]);
  } else {
    int i = (bid - 2304) * 256 + threadIdx.x;
    if (i < NEE) atomicAdd(cnt + didx[i], 1);
  }
}

__global__ void csr_scan(const int* __restrict__ cnt, int* __restrict__ cursor) {
  __shared__ int psum[256];
  const int CH = (NMN + 255) / 256;
  int t = threadIdx.x;
  int base = t * CH, s = 0;
  for (int k = 0; k < CH; ++k) { int i = base + k; if (i < NMN) s += cnt[i]; }
  psum[t] = s;
  __syncthreads();
  for (int off = 1; off < 256; off <<= 1) {
    int v = (t >= off) ? psum[t - off] : 0;
    __syncthreads();
    psum[t] += v;
    __syncthreads();
  }
  int run = psum[t] - s;
  for (int k = 0; k < CH; ++k) {
    int i = base + k;
    if (i < NMN) { cursor[i] = run; run += cnt[i]; }
  }
}

// ---------------- GEMM body (dense, bf16 out) ----------------
__device__ __forceinline__ void gemm_body(u16* uni, const float* __restrict__ X,
                                          const u16* __restrict__ Wp, u16* __restrict__ Y,
                                          int n, int blk) {
  const int tid = threadIdx.x;
  const int lane = tid & 63;
  const int wave = tid >> 6;
  const int mr = wave >> 1, nc = wave & 1;
  const int g = lane >> 4, lr = lane & 15;
  const int row0 = blk * 64;

#pragma unroll
  for (int j = 0; j < 8; ++j) {
    int e = wave * 16 + j * 2 + (lane >> 5);
    int r = min(row0 + e, n - 1);
    const float* src = X + (size_t)r * DD + (lane & 31) * 8;
    f32x4 f0 = *(const f32x4*)src;
    f32x4 f1 = *(const f32x4*)(src + 4);
    s16x8 o;
#pragma unroll
    for (int k = 0; k < 4; ++k) { o[k] = (short)f2bf(f0[k]); o[4 + k] = (short)f2bf(f1[k]); }
    int co = (lane & 31) * 8;
    *(s16x8*)((char*)uni + e * 512 + ((co * 2) ^ ((e & 7) << 4))) = o;
  }
  __syncthreads();

  const f32x4 fz = {0.f, 0.f, 0.f, 0.f};
  f32x4 acc[2][8];
#pragma unroll
  for (int mt = 0; mt < 2; ++mt)
#pragma unroll
    for (int nt = 0; nt < 8; ++nt) acc[mt][nt] = fz;

  for (int kl = 0; kl < 8; ++kl) {
    s16x8 afr[2];
#pragma unroll
    for (int mt = 0; mt < 2; ++mt) afr[mt] = ldsA(uni, mr * 32 + mt * 16 + lr, kl * 32 + 4 * g);
#pragma unroll
    for (int h = 0; h < 2; ++h) {
      s16x8 bfr[4];
#pragma unroll
      for (int q = 0; q < 4; ++q)
        bfr[q] = *(const s16x8*)(Wp + (size_t)kl * 8192 + ((nc * 8 + h * 4 + q) * 64 + lane) * 8);
#pragma unroll
      for (int q = 0; q < 4; ++q) {
        acc[0][h * 4 + q] = __builtin_amdgcn_mfma_f32_16x16x32_bf16(afr[0], bfr[q], acc[0][h * 4 + q], 0, 0, 0);
        acc[1][h * 4 + q] = __builtin_amdgcn_mfma_f32_16x16x32_bf16(afr[1], bfr[q], acc[1][h * 4 + q], 0, 0, 0);
      }
    }
  }
  __syncthreads();
#pragma unroll
  for (int mt = 0; mt < 2; ++mt)
#pragma unroll
    for (int nt = 0; nt < 8; ++nt)
#pragma unroll
      for (int i = 0; i < 4; ++i) {
        int rowL = mr * 32 + mt * 16 + 4 * g + i;
        int col = nc * 128 + nt * 16 + lr;
        *(u16*)((char*)uni + rowL * 512 + ((col * 2) ^ ((rowL & 7) << 4))) = f2bf(acc[mt][nt][i]);
      }
  __syncthreads();
#pragma unroll
  for (int rr = 0; rr < 16; ++rr) {
    int rowL = wave * 16 + rr;
    int rg = row0 + rowL;
    if (rg < n) {
      s16x4 v = *(const s16x4*)((char*)uni + rowL * 512 + ((lane * 8) ^ ((rowL & 7) << 4)));
      *(s16x4*)(Y + (size_t)rg * DD + lane * 4) = v;
    }
  }
}

// gemm_GS (1250) | gemm_GM (313) | csr_fill (625)
__global__ __launch_bounds__(256, 2) void gemm_fill(
    const float* __restrict__ gridf, const float* __restrict__ mesh,
    const u16* __restrict__ wp, u16* __restrict__ GSp, u16* __restrict__ GMp,
    const int* __restrict__ didx, int* __restrict__ cursor, int* __restrict__ eids) {
  __shared__ u16 uni[16384];
  int bid = blockIdx.x;
  if (bid < 1250) gemm_body(uni, gridf, wp + 8 * 8192, GSp, NGN, bid);
  else if (bid < 1563) gemm_body(uni, mesh, wp + 16 * 8192, GMp, NMN, bid - 1250);
  else {
    int e = (bid - 1563) * 256 + threadIdx.x;
    if (e < NEE) { int p = atomicAdd(cursor + didx[e], 1); eids[p] = e; }
  }
}

// ---------------- node MLP body ----------------
template <int MODE, int K1>
__device__ __forceinline__ void mlp_body(
    u16* uni, float2 (*pstats)[2],
    const float* __restrict__ xa, const float* __restrict__ xb,
    const u16* __restrict__ W1p, const float* __restrict__ b1,
    const u16* __restrict__ W2p, const float* __restrict__ b2,
    const float* __restrict__ gam, const float* __restrict__ bet,
    const float* __restrict__ resid, float* __restrict__ out, int nrows, int blk) {
  const int tid = threadIdx.x;
  const int lane = tid & 63;
  const int wave = tid >> 6;
  const int mr = wave >> 1, nc = wave & 1;
  const int g = lane >> 4, lr = lane & 15;
  const int row0 = blk * 64;

  const f32x4 fz = {0.f, 0.f, 0.f, 0.f};
  f32x4 acc[2][8];
#pragma unroll
  for (int mt = 0; mt < 2; ++mt)
#pragma unroll
    for (int nt = 0; nt < 8; ++nt) acc[mt][nt] = fz;

#pragma unroll
  for (int region = 0; region < K1 / 256; ++region) {
    __syncthreads();
    const float* Xr = (region == 0) ? xa : xb;
#pragma unroll
    for (int j = 0; j < 8; ++j) {
      int e = wave * 16 + j * 2 + (lane >> 5);
      int r = min(row0 + e, nrows - 1);
      const float* src = Xr + (size_t)r * DD + (lane & 31) * 8;
      f32x4 f0 = *(const f32x4*)src;
      f32x4 f1 = *(const f32x4*)(src + 4);
      s16x8 o;
#pragma unroll
      for (int k = 0; k < 4; ++k) { o[k] = (short)f2bf(f0[k]); o[4 + k] = (short)f2bf(f1[k]); }
      int co = (lane & 31) * 8;
      *(s16x8*)((char*)uni + e * 512 + ((co * 2) ^ ((e & 7) << 4))) = o;
    }
    __syncthreads();
    for (int kl = 0; kl < 8; ++kl) {
      const int kt = region * 8 + kl;
      s16x8 afr[2];
#pragma unroll
      for (int mt = 0; mt < 2; ++mt) afr[mt] = ldsA(uni, mr * 32 + mt * 16 + lr, kl * 32 + 4 * g);
#pragma unroll
      for (int h = 0; h < 2; ++h) {
        s16x8 bfr[4];
#pragma unroll
        for (int q = 0; q < 4; ++q)
          bfr[q] = *(const s16x8*)(W1p + (size_t)kt * 8192 + ((nc * 8 + h * 4 + q) * 64 + lane) * 8);
#pragma unroll
        for (int q = 0; q < 4; ++q) {
          acc[0][h * 4 + q] = __builtin_amdgcn_mfma_f32_16x16x32_bf16(afr[0], bfr[q], acc[0][h * 4 + q], 0, 0, 0);
          acc[1][h * 4 + q] = __builtin_amdgcn_mfma_f32_16x16x32_bf16(afr[1], bfr[q], acc[1][h * 4 + q], 0, 0, 0);
        }
      }
    }
  }
  __syncthreads();

  {
    float b1v[8];
#pragma unroll
    for (int nt = 0; nt < 8; ++nt) b1v[nt] = b1[nc * 128 + nt * 16 + lr];
#pragma unroll
    for (int mt = 0; mt < 2; ++mt)
#pragma unroll
      for (int nt = 0; nt < 8; ++nt)
#pragma unroll
        for (int i = 0; i < 4; ++i) {
          float x = acc[mt][nt][i] + b1v[nt];
          float h = x / (1.f + __expf(-x));
          int rowL = mr * 32 + mt * 16 + 4 * g + i;
          int col = nc * 128 + nt * 16 + lr;
          *(u16*)((char*)uni + rowL * 512 + ((col * 2) ^ ((rowL & 7) << 4))) = f2bf(h);
        }
  }
  __syncthreads();

  f32x4 acc2[2][8];
#pragma unroll
  for (int mt = 0; mt < 2; ++mt)
#pragma unroll
    for (int nt = 0; nt < 8; ++nt) acc2[mt][nt] = fz;
  for (int kl = 0; kl < 8; ++kl) {
    s16x8 afr[2];
#pragma unroll
    for (int mt = 0; mt < 2; ++mt) afr[mt] = ldsA(uni, mr * 32 + mt * 16 + lr, kl * 32 + 4 * g);
#pragma unroll
    for (int h = 0; h < 2; ++h) {
      s16x8 bfr[4];
#pragma unroll
      for (int q = 0; q < 4; ++q)
        bfr[q] = *(const s16x8*)(W2p + (size_t)kl * 8192 + ((nc * 8 + h * 4 + q) * 64 + lane) * 8);
#pragma unroll
      for (int q = 0; q < 4; ++q) {
        acc2[0][h * 4 + q] = __builtin_amdgcn_mfma_f32_16x16x32_bf16(afr[0], bfr[q], acc2[0][h * 4 + q], 0, 0, 0);
        acc2[1][h * 4 + q] = __builtin_amdgcn_mfma_f32_16x16x32_bf16(afr[1], bfr[q], acc2[1][h * 4 + q], 0, 0, 0);
      }
    }
  }

  float b2v[8], gv[8], bv[8];
#pragma unroll
  for (int nt = 0; nt < 8; ++nt) {
    int col = nc * 128 + nt * 16 + lr;
    b2v[nt] = b2[col];
    gv[nt] = gam[col];
    bv[nt] = bet[col];
  }
#pragma unroll
  for (int mt = 0; mt < 2; ++mt)
#pragma unroll
    for (int i = 0; i < 4; ++i) {
      float s = 0.f, s2 = 0.f;
#pragma unroll
      for (int nt = 0; nt < 8; ++nt) {
        float y = acc2[mt][nt][i] + b2v[nt];
        s += y;
        s2 += y * y;
      }
#pragma unroll
      for (int m = 1; m < 16; m <<= 1) {
        s += __shfl_xor(s, m);
        s2 += __shfl_xor(s2, m);
      }
      if (lr == 0) pstats[mr * 32 + mt * 16 + 4 * g + i][nc] = make_float2(s, s2);
    }
  __syncthreads();
#pragma unroll
  for (int mt = 0; mt < 2; ++mt)
#pragma unroll
    for (int i = 0; i < 4; ++i) {
      int rowL = mr * 32 + mt * 16 + 4 * g + i;
      float2 pa = pstats[rowL][0], pb = pstats[rowL][1];
      float sum = pa.x + pb.x, sq = pa.y + pb.y;
      float mu = sum * (1.f / 256.f);
      float var = fmaxf(sq * (1.f / 256.f) - mu * mu, 0.f);
      float rs = rsqrtf(var + 1e-5f);
      int rg = row0 + rowL;
      if (MODE == 2 && rg >= nrows) continue;
#pragma unroll
      for (int nt = 0; nt < 8; ++nt) {
        int col = nc * 128 + nt * 16 + lr;
        float y = acc2[mt][nt][i] + b2v[nt];
        float val = (y - mu) * rs * gv[nt] + bv[nt];
        out[(size_t)rg * DD + col] = resid[(size_t)rg * DD + col] + val;
      }
    }
}

// ---------------- edge body (CSR run-reduced scatter) ----------------
__device__ __forceinline__ void edge_body(
    u16* uni, float2 (*pstats)[2], int* eidL, int* srcL, int* dstL,
    const float* __restrict__ efeat,
    const u16* __restrict__ GSp, const u16* __restrict__ GMp,
    const int* __restrict__ sidx, const int* __restrict__ eids,
    const u16* __restrict__ W1p, const float* __restrict__ b1,
    const u16* __restrict__ W2p, const float* __restrict__ b2,
    const float* __restrict__ gam, const float* __restrict__ bet,
    const int* __restrict__ didx, float* __restrict__ agg, int blk) {
  const int tid = threadIdx.x;
  const int lane = tid & 63;
  const int wave = tid >> 6;
  const int mr = wave >> 1, nc = wave & 1;
  const int g = lane >> 4, lr = lane & 15;
  const int row0 = blk * 64;

  if (tid < 64) {
    int e = eids[row0 + tid];
    eidL[tid] = e;
    srcL[tid] = sidx[e];
    dstL[tid] = didx[e];
  }
  __syncthreads();

#pragma unroll
  for (int j = 0; j < 8; ++j) {
    int e = wave * 16 + j * 2 + (lane >> 5);
    int co = (lane & 31) * 8;
    s16x8 a = *(const s16x8*)(GSp + (size_t)srcL[e] * DD + co);
    s16x8 b = *(const s16x8*)(GMp + (size_t)dstL[e] * DD + co);
    s16x8 o;
#pragma unroll
    for (int k2 = 0; k2 < 8; ++k2)
      o[k2] = (short)f2bf(bf2f((u16)a[k2]) + bf2f((u16)b[k2]));
    *(s16x8*)((char*)uni + e * 512 + ((co * 2) ^ ((e & 7) << 4))) = o;
  }
  __syncthreads();

  f32x4 acc[2][8];
#pragma unroll
  for (int mt = 0; mt < 2; ++mt)
#pragma unroll
    for (int nt = 0; nt < 8; ++nt)
#pragma unroll
      for (int i = 0; i < 4; ++i) {
        int rowL = mr * 32 + mt * 16 + 4 * g + i;
        int col = nc * 128 + nt * 16 + lr;
        acc[mt][nt][i] = bf2f(*(const u16*)((char*)uni + rowL * 512 + ((col * 2) ^ ((rowL & 7) << 4))));
      }
  __syncthreads();

#pragma unroll
  for (int j = 0; j < 8; ++j) {
    int e = wave * 16 + j * 2 + (lane >> 5);
    const float* src = efeat + (size_t)eidL[e] * DD + (lane & 31) * 8;
    f32x4 f0 = *(const f32x4*)src;
    f32x4 f1 = *(const f32x4*)(src + 4);
    s16x8 o;
#pragma unroll
    for (int k = 0; k < 4; ++k) { o[k] = (short)f2bf(f0[k]); o[4 + k] = (short)f2bf(f1[k]); }
    int co = (lane & 31) * 8;
    *(s16x8*)((char*)uni + e * 512 + ((co * 2) ^ ((e & 7) << 4))) = o;
  }
  __syncthreads();

  for (int kl = 0; kl < 8; ++kl) {
    s16x8 afr[2];
#pragma unroll
    for (int mt = 0; mt < 2; ++mt) afr[mt] = ldsA(uni, mr * 32 + mt * 16 + lr, kl * 32 + 4 * g);
#pragma unroll
    for (int h = 0; h < 2; ++h) {
      s16x8 bfr[4];
#pragma unroll
      for (int q = 0; q < 4; ++q)
        bfr[q] = *(const s16x8*)(W1p + (size_t)kl * 8192 + ((nc * 8 + h * 4 + q) * 64 + lane) * 8);
#pragma unroll
      for (int q = 0; q < 4; ++q) {
        acc[0][h * 4 + q] = __builtin_amdgcn_mfma_f32_16x16x32_bf16(afr[0], bfr[q], acc[0][h * 4 + q], 0, 0, 0);
        acc[1][h * 4 + q] = __builtin_amdgcn_mfma_f32_16x16x32_bf16(afr[1], bfr[q], acc[1][h * 4 + q], 0, 0, 0);
      }
    }
  }
  __syncthreads();

  {
    float b1v[8];
#pragma unroll
    for (int nt = 0; nt < 8; ++nt) b1v[nt] = b1[nc * 128 + nt * 16 + lr];
#pragma unroll
    for (int mt = 0; mt < 2; ++mt)
#pragma unroll
      for (int nt = 0; nt < 8; ++nt)
#pragma unroll
        for (int i = 0; i < 4; ++i) {
          float x = acc[mt][nt][i] + b1v[nt];
          float h = x / (1.f + __expf(-x));
          int rowL = mr * 32 + mt * 16 + 4 * g + i;
          int col = nc * 128 + nt * 16 + lr;
          *(u16*)((char*)uni + rowL * 512 + ((col * 2) ^ ((rowL & 7) << 4))) = f2bf(h);
        }
  }
  __syncthreads();

  f32x4 acc2[2][8];
  const f32x4 fz = {0.f, 0.f, 0.f, 0.f};
#pragma unroll
  for (int mt = 0; mt < 2; ++mt)
#pragma unroll
    for (int nt = 0; nt < 8; ++nt) acc2[mt][nt] = fz;
  for (int kl = 0; kl < 8; ++kl) {
    s16x8 afr[2];
#pragma unroll
    for (int mt = 0; mt < 2; ++mt) afr[mt] = ldsA(uni, mr * 32 + mt * 16 + lr, kl * 32 + 4 * g);
#pragma unroll
    for (int h = 0; h < 2; ++h) {
      s16x8 bfr[4];
#pragma unroll
      for (int q = 0; q < 4; ++q)
        bfr[q] = *(const s16x8*)(W2p + (size_t)kl * 8192 + ((nc * 8 + h * 4 + q) * 64 + lane) * 8);
#pragma unroll
      for (int q = 0; q < 4; ++q) {
        acc2[0][h * 4 + q] = __builtin_amdgcn_mfma_f32_16x16x32_bf16(afr[0], bfr[q], acc2[0][h * 4 + q], 0, 0, 0);
        acc2[1][h * 4 + q] = __builtin_amdgcn_mfma_f32_16x16x32_bf16(afr[1], bfr[q], acc2[1][h * 4 + q], 0, 0, 0);
      }
    }
  }

  float b2v[8], gv[8], bv[8];
#pragma unroll
  for (int nt = 0; nt < 8; ++nt) {
    int col = nc * 128 + nt * 16 + lr;
    b2v[nt] = b2[col];
    gv[nt] = gam[col];
    bv[nt] = bet[col];
  }
#pragma unroll
  for (int mt = 0; mt < 2; ++mt)
#pragma unroll
    for (int i = 0; i < 4; ++i) {
      float s = 0.f, s2 = 0.f;
#pragma unroll
      for (int nt = 0; nt < 8; ++nt) {
        float y = acc2[mt][nt][i] + b2v[nt];
        s += y;
        s2 += y * y;
      }
#pragma unroll
      for (int m = 1; m < 16; m <<= 1) {
        s += __shfl_xor(s, m);
        s2 += __shfl_xor(s2, m);
      }
      if (lr == 0) pstats[mr * 32 + mt * 16 + 4 * g + i][nc] = make_float2(s, s2);
    }
  __syncthreads();

#pragma unroll
  for (int mt = 0; mt < 2; ++mt)
#pragma unroll
    for (int i = 0; i < 4; ++i) {
      int rowL = mr * 32 + mt * 16 + 4 * g + i;
      float2 pa = pstats[rowL][0], pb = pstats[rowL][1];
      float sum = pa.x + pb.x, sq = pa.y + pb.y;
      float mu = sum * (1.f / 256.f);
      float var = fmaxf(sq * (1.f / 256.f) - mu * mu, 0.f);
      float rs = rsqrtf(var + 1e-5f);
#pragma unroll
      for (int nt = 0; nt < 8; ++nt) {
        int col = nc * 128 + nt * 16 + lr;
        float y = acc2[mt][nt][i] + b2v[nt];
        float val = (y - mu) * rs * gv[nt] + bv[nt];
        *(u16*)((char*)uni + rowL * 512 + ((col * 2) ^ ((rowL & 7) << 4))) = f2bf(val);
      }
    }
  __syncthreads();

  {
    int c = tid;
    float sum = 0.f;
    int prev = dstL[0];
#pragma unroll 8
    for (int r = 0; r < 64; ++r) {
      int d = dstL[r];
      if (d != prev) {
        atomicAdd(agg + (size_t)prev * DD + c, sum);
        sum = 0.f;
        prev = d;
      }
      sum += bf2f(*(const u16*)((char*)uni + r * 512 + ((c * 2) ^ ((r & 7) << 4))));
    }
    atomicAdd(agg + (size_t)prev * DD + c, sum);
  }
}

// ---------------- merged edge + grid-MLP dispatch ----------------
__global__ __launch_bounds__(256, 2) void edge_mlp(
    const float* __restrict__ efeat,
    const u16* __restrict__ GSp, const u16* __restrict__ GMp,
    const int* __restrict__ sidx, const int* __restrict__ eids,
    const u16* __restrict__ eW1p, const float* __restrict__ eb1,
    const u16* __restrict__ eW2p, const float* __restrict__ eb2,
    const float* __restrict__ eg, const float* __restrict__ ebt,
    const int* __restrict__ didx, float* __restrict__ agg,
    const float* __restrict__ gridf,
    const u16* __restrict__ sW1p, const float* __restrict__ sb1,
    const u16* __restrict__ sW2p, const float* __restrict__ sb2,
    const float* __restrict__ sg, const float* __restrict__ sbt,
    float* __restrict__ gout, int withMlp) {
  __shared__ u16 uni[16384];
  __shared__ float2 pstats[64][2];
  __shared__ int eidL[64], srcL[64], dstL[64];
  int bid = blockIdx.x;
  if (withMlp) {
    if ((bid % 3) == 2) {
      mlp_body<1, 256>(uni, pstats, gridf, nullptr, sW1p, sb1, sW2p, sb2,
                       sg, sbt, gridf, gout, NGN, bid / 3);
      return;
    }
    bid = (bid / 3) * 2 + (bid % 3);
  }
  edge_body(uni, pstats, eidL, srcL, dstL, efeat, GSp, GMp, sidx, eids,
            eW1p, eb1, eW2p, eb2, eg, ebt, didx, agg, bid);
}

__global__ __launch_bounds__(256, 2) void mlp1_kernel(
    const float* __restrict__ gridf,
    const u16* __restrict__ W1p, const float* __restrict__ b1,
    const u16* __restrict__ W2p, const float* __restrict__ b2,
    const float* __restrict__ gam, const float* __restrict__ bet,
    float* __restrict__ out) {
  __shared__ u16 uni[16384];
  __shared__ float2 pstats[64][2];
  mlp_body<1, 256>(uni, pstats, gridf, nullptr, W1p, b1, W2p, b2, gam, bet,
                   gridf, out, NGN, blockIdx.x);
}

__global__ __launch_bounds__(256, 2) void mlp2_kernel(
    const float* __restrict__ agg, const float* __restrict__ mesh,
    const u16* __restrict__ W1p, const float* __restrict__ b1,
    const u16* __restrict__ W2p, const float* __restrict__ b2,
    const float* __restrict__ gam, const float* __restrict__ bet,
    float* __restrict__ out) {
  __shared__ u16 uni[16384];
  __shared__ float2 pstats[64][2];
  mlp_body<2, 512>(uni, pstats, agg, mesh, W1p, b1, W2p, b2, gam, bet,
                   mesh, out, NMN, blockIdx.x);
}

extern "C" void kernel_launch(void* const* d_in, const int* in_sizes, int n_in,
                              void* d_out, int out_size, void* d_ws, size_t ws_size,
                              hipStream_t stream) {
  const float* g2m  = (const float*)d_in[0];
  const float* grid = (const float*)d_in[1];
  const float* mesh = (const float*)d_in[2];
  const int* sidx = (const int*)d_in[3];
  const int* didx = (const int*)d_in[4];
  const float* eW1 = (const float*)d_in[5];
  const float* eb1 = (const float*)d_in[6];
  const float* eW2 = (const float*)d_in[7];
  const float* eb2 = (const float*)d_in[8];
  const float* eg  = (const float*)d_in[9];
  const float* ebt = (const float*)d_in[10];
  const float* sW1 = (const float*)d_in[11];
  const float* sb1 = (const float*)d_in[12];
  const float* sW2 = (const float*)d_in[13];
  const float* sb2 = (const float*)d_in[14];
  const float* sg  = (const float*)d_in[15];
  const float* sbt = (const float*)d_in[16];
  const float* dW1 = (const float*)d_in[17];
  const float* db1 = (const float*)d_in[18];
  const float* dW2 = (const float*)d_in[19];
  const float* db2 = (const float*)d_in[20];
  const float* dg  = (const float*)d_in[21];
  const float* dbt = (const float*)d_in[22];

  // workspace layout
  char* w = (char*)d_ws;
  float* agg = (float*)w;                       // 20,480,000 B
  u16* wp = (u16*)(w + 20480000);               // 1,179,648 B
  int* cnt = (int*)(w + 20480000 + 1179648);    // 81,920
  int* cursor = cnt + 20480;                    // 81,920
  int* eids = cursor + 20480;                   // 640,000  (ends 22,463,488)
  const size_t GS_OFF = 22463488;
  const size_t NEEDED = GS_OFF + (size_t)NGN * DD * 2 + (size_t)NMN * DD * 2;  // 73,663,488

  u16* eW1p = wp;
  u16* eW2p = eW1p + 768 * 256;
  u16* sW1p = eW2p + 256 * 256;
  u16* sW2p = sW1p + 256 * 256;
  u16* dW1p = sW2p + 256 * 256;
  u16* dW2p = dW1p + 512 * 256;

  float* gout = (float*)d_out;
  float* mout = gout + (size_t)NGN * DD;

  const bool big = ws_size >= NEEDED;
  u16* GSp = big ? (u16*)(w + GS_OFF) : (u16*)d_out;
  u16* GMp = GSp + (size_t)NGN * DD;

  (void)hipMemsetAsync(agg, 0, 20480000, stream);
  (void)hipMemsetAsync(cnt, 0, 81920, stream);

  pack_hist<<<2304 + 625, 256, 0, stream>>>(eW1, eW2, sW1, sW2, dW1, dW2, wp, didx, cnt);
  csr_scan<<<1, 256, 0, stream>>>(cnt, cursor);
  gemm_fill<<<1563 + 625, 256, 0, stream>>>(grid, mesh, wp, GSp, GMp, didx, cursor, eids);

  if (big) {
    // edge (2500) + grid MLP (1250) interleaved 2:1 in one dispatch
    edge_mlp<<<3750, 256, 0, stream>>>(
        g2m, GSp, GMp, sidx, eids, eW1p, eb1, eW2p, eb2, eg, ebt, didx, agg,
        grid, sW1p, sb1, sW2p, sb2, sg, sbt, gout, 1);
    mlp2_kernel<<<(NMN + 63) / 64, 256, 0, stream>>>(
        agg, mesh, dW1p, db1, dW2p, db2, dg, dbt, mout);
  } else {
    // GS/GM live in d_out's grid half: grid MLP must run last
    edge_mlp<<<2500, 256, 0, stream>>>(
        g2m, GSp, GMp, sidx, eids, eW1p, eb1, eW2p, eb2, eg, ebt, didx, agg,
        grid, sW1p, sb1, sW2p, sb2, sg, sbt, gout, 0);
    mlp2_kernel<<<(NMN + 63) / 64, 256, 0, stream>>>(
        agg, mesh, dW1p, db1, dW2p, db2, dg, dbt, mout);
    mlp1_kernel<<<NGN / 64, 256, 0, stream>>>(
        grid, sW1p, sb1, sW2p, sb2, sg, sbt, gout);
  }
}